// Round 3
// baseline (268.466 us; speedup 1.0000x reference)
//
#include <hip/hip_runtime.h>

#define NN 400
#define HID 96
#define EDGES 79800
#define BATCH 16
#define ROWS (BATCH*EDGES)
#define NTILES 4988
#define NBLK 768

typedef _Float16 f16;
typedef f16 f16x2 __attribute__((ext_vector_type(2)));
typedef f16 f16x8 __attribute__((ext_vector_type(8)));
typedef __fp16 fp16x2 __attribute__((ext_vector_type(2)));
typedef float f32x16 __attribute__((ext_vector_type(16)));
typedef unsigned int u32;

union H8 { f16x8 h; u32 u[4]; f16x2 p[4]; fp16x2 q[4]; };
union C2 { f16x2 h; fp16x2 q; u32 u; };

__device__ inline f16x2 pkrtz(float a, float b) {
  C2 c; c.q = __builtin_amdgcn_cvt_pkrtz(a, b); return c.h;
}
__device__ inline u32 pkrtz_u(float a, float b) {
  C2 c; c.q = __builtin_amdgcn_cvt_pkrtz(a, b); return c.u;
}
__device__ inline float fdot2a(f16x2 a, f16x2 b, float c) {
#if __has_builtin(__builtin_amdgcn_fdot2)
  C2 ca, cb; ca.h = a; cb.h = b;
  return __builtin_amdgcn_fdot2(ca.q, cb.q, c, false);
#else
  return c + (float)a.x*(float)b.x + (float)a.y*(float)b.y;
#endif
}

__device__ inline f16x8 habs8(f16x8 x) {
  H8 t; t.h = x;
  t.u[0] &= 0x7fff7fffu; t.u[1] &= 0x7fff7fffu;
  t.u[2] &= 0x7fff7fffu; t.u[3] &= 0x7fff7fffu;
  return t.h;
}

__device__ inline f16x8 pack8(float a0,float a1,float a2,float a3,
                              float a4,float a5,float a6,float a7){
  H8 u;
  u.p[0] = pkrtz(a0,a1);
  u.p[1] = pkrtz(a2,a3);
  u.p[2] = pkrtz(a4,a5);
  u.p[3] = pkrtz(a6,a7);
  return u.h;
}

// ---------------- prep: zero msum + swizzle all 4 weight matrices into MFMA frag order ----------
// wq regions (dwords): Wd1 [0,9216)  Wd2-permK [9216,11264)  We1 [11264,31232)  We2 [31232,35840)
// frag dword D = ((t*CT+ct)*64+lane)*4+dj ; k = 16t+8h2+2dj ; d = 32*ct + c
__global__ void prep_kernel(const float* __restrict__ We1, const float* __restrict__ We2,
                            const float* __restrict__ W1, const float* __restrict__ W2,
                            u32* __restrict__ wq, float* __restrict__ msum) {
  int D = blockIdx.x*256 + threadIdx.x;
  if (blockIdx.x == 0 && threadIdx.x < 16) msum[threadIdx.x] = 0.f;
  if (D >= 35840) return;
  float v0, v1;
  if (D < 9216) {               // W_d1 B-frags (288 x 64), d = 32q+c
    int frag = D >> 8;  int t = frag >> 1, q = frag & 1;
    int rem = D & 255;  int lane = rem >> 2, dj = rem & 3;
    int c = lane & 31, h2 = lane >> 5;
    int k = 16*t + 8*h2 + 2*dj;
    int d = 32*q + c;
    v0 = W1[k*64 + d]; v1 = W1[(k+1)*64 + d];
  } else if (D < 11264) {       // W_d2 B-frags, K permuted: pair sources (p, p+32)
    int Dl = D - 9216;
    int frag = Dl >> 8; int t2 = frag >> 1, q = frag & 1;
    int rem = Dl & 255; int lane = rem >> 2, dj = rem & 3;
    int c = lane & 31, h2 = lane >> 5;
    int p = 8*t2 + 4*h2 + dj;
    int d = 32*q + c;
    v0 = W2[p*64 + d]; v1 = W2[(p+32)*64 + d];
  } else if (D < 31232) {       // W_e1 frags (416 x 96), feature-permuted (sc first, static at 400)
    int Dl = D - 11264;
    int frag = Dl >> 8; int t = frag/3, ct = frag - 3*t;
    int rem = Dl & 255; int lane = rem >> 2, dj = rem & 3;
    int c = lane & 31, h2 = lane >> 5;
    int k0 = 16*t + 8*h2 + 2*dj, k1 = k0 + 1;
    int d = 32*ct + c;
    v0 = (k0 < 400) ? We1[(8+k0)*96 + d] : (k0 < 408 ? We1[(k0-400)*96 + d] : 0.f);
    v1 = (k1 < 400) ? We1[(8+k1)*96 + d] : (k1 < 408 ? We1[(k1-400)*96 + d] : 0.f);
  } else {                      // W_e2 frags (96 x 96)
    int Dl = D - 31232;
    int frag = Dl >> 8; int t = frag/3, ct = frag - 3*t;
    int rem = Dl & 255; int lane = rem >> 2, dj = rem & 3;
    int c = lane & 31, h2 = lane >> 5;
    int k = 16*t + 8*h2 + 2*dj;
    int d = 32*ct + c;
    v0 = We2[k*96 + d]; v1 = We2[(k+1)*96 + d];
  }
  wq[D] = pkrtz_u(v0, v1);
}

// ---------------- per-batch mean of sc_matrix ----------------
__global__ void mean_kernel(const float* __restrict__ sc, float* __restrict__ msum) {
  int b = blockIdx.x >> 2, part = blockIdx.x & 3;
  const float4* p = (const float4*)(sc + (size_t)b*160000) + part*10000;
  float s = 0.f;
  for (int i = threadIdx.x; i < 10000; i += 256) {
    float4 v = p[i];
    s += (v.x + v.y) + (v.z + v.w);
  }
  __shared__ float red[256];
  red[threadIdx.x] = s; __syncthreads();
  for (int off = 128; off > 0; off >>= 1) {
    if (threadIdx.x < off) red[threadIdx.x] += red[threadIdx.x + off];
    __syncthreads();
  }
  if (threadIdx.x == 0) atomicAdd(&msum[b], red[0]);
}

// ---------------- enc1: feats (JIT from sc/nf) @ We1 -> prelu -> g1 f16 [6400 x 96] -------------
__global__ __launch_bounds__(256) void enc1_kernel(
    const float* __restrict__ sc, const float* __restrict__ nf,
    const float* __restrict__ smean, const float* __restrict__ sstd,
    const float* __restrict__ be1, const float* __restrict__ ae1,
    const float* __restrict__ msum, const u32* __restrict__ wq,
    f16* __restrict__ g1) {
  int wid = threadIdx.x >> 6, lane = threadIdx.x & 63;
  int rt = blockIdx.x*4 + wid;          // 0..199
  int c = lane & 31, h2 = lane >> 5;
  int r = rt*32 + c;                    // flat row (b*400+n)
  int b = r / 400;
  float rm = 1.f / fmaxf(msum[b]*(1.f/160000.f), 1e-8f);
  float a = *ae1;
  f32x16 acc[3];
#pragma unroll
  for (int q = 0; q < 3; ++q) {
    float bv = be1[32*q + c];
#pragma unroll
    for (int i = 0; i < 16; ++i) acc[q][i] = bv;
  }
  const u32* wb = wq + 11264;
  const float* scr = sc + (size_t)r*400;
#pragma unroll 4
  for (int t = 0; t < 25; ++t) {
    int k0 = 16*t + 8*h2;
    float4 s0 = *(const float4*)(scr + k0);
    float4 s1 = *(const float4*)(scr + k0 + 4);
    f16x8 af = pack8(s0.x*rm, s0.y*rm, s0.z*rm, s0.w*rm,
                     s1.x*rm, s1.y*rm, s1.z*rm, s1.w*rm);
#pragma unroll
    for (int ct = 0; ct < 3; ++ct) {
      f16x8 bf = *(const f16x8*)(wb + ((t*3+ct)*64 + lane)*4);
      acc[ct] = __builtin_amdgcn_mfma_f32_32x32x16_f16(af, bf, acc[ct], 0,0,0);
    }
  }
  {
    // t = 25: k 400..407 = static features (h2==0), 408..415 = zero pad
    f16x8 af = {};
    if (h2 == 0) {
      float q0[8];
#pragma unroll
      for (int j = 0; j < 8; ++j)
        q0[j] = (nf[r*8 + j] - smean[j]) / (sstd[j] + 1e-8f);
      af = pack8(q0[0],q0[1],q0[2],q0[3],q0[4],q0[5],q0[6],q0[7]);
    }
#pragma unroll
    for (int ct = 0; ct < 3; ++ct) {
      f16x8 bf = *(const f16x8*)(wb + ((25*3+ct)*64 + lane)*4);
      acc[ct] = __builtin_amdgcn_mfma_f32_32x32x16_f16(af, bf, acc[ct], 0,0,0);
    }
  }
#pragma unroll
  for (int ct = 0; ct < 3; ++ct)
#pragma unroll
    for (int rr = 0; rr < 16; ++rr) {
      int row = (rr & 3) + 8*(rr >> 2) + 4*h2;
      float v = acc[ct][rr]; v = fmaxf(v, a*v);
      g1[(rt*32 + row)*96 + 32*ct + c] = (f16)v;
    }
}

// ---------------- enc2: g1 @ We2 -> prelu -> h f16 [6400 x 96] ----------------
__global__ __launch_bounds__(256) void enc2_kernel(
    const f16* __restrict__ g1, const float* __restrict__ be2,
    const float* __restrict__ ae2, const u32* __restrict__ wq,
    f16* __restrict__ hout) {
  int wid = threadIdx.x >> 6, lane = threadIdx.x & 63;
  int rt = blockIdx.x*4 + wid;
  int c = lane & 31, h2 = lane >> 5;
  int r = rt*32 + c;
  float a = *ae2;
  f32x16 acc[3];
#pragma unroll
  for (int q = 0; q < 3; ++q) {
    float bv = be2[32*q + c];
#pragma unroll
    for (int i = 0; i < 16; ++i) acc[q][i] = bv;
  }
  const u32* wb = wq + 31232;
#pragma unroll
  for (int t = 0; t < 6; ++t) {
    f16x8 af = *(const f16x8*)(g1 + r*96 + 16*t + 8*h2);
#pragma unroll
    for (int ct = 0; ct < 3; ++ct) {
      f16x8 bf = *(const f16x8*)(wb + ((t*3+ct)*64 + lane)*4);
      acc[ct] = __builtin_amdgcn_mfma_f32_32x32x16_f16(af, bf, acc[ct], 0,0,0);
    }
  }
#pragma unroll
  for (int ct = 0; ct < 3; ++ct)
#pragma unroll
    for (int rr = 0; rr < 16; ++rr) {
      int row = (rr & 3) + 8*(rr >> 2) + 4*h2;
      float v = acc[ct][rr]; v = fmaxf(v, a*v);
      hout[(rt*32 + row)*96 + 32*ct + c] = (f16)v;
    }
}

// ---------------- decoder: per-edge 3-layer MLP via f16 MFMA ----------------
// d-mapping: col c of acc q holds dim 32q+c. z1/z2 pack pairs (d, d+32) per dword;
// W_d2 K-order is permuted to match (done in prep). LDS 53,248 B -> 3 blocks/CU.
__global__ __launch_bounds__(256, 3) void decoder_kernel(
    const f16* __restrict__ hbuf, const u32* __restrict__ wq,
    const float* __restrict__ b1, const float* __restrict__ b2,
    const float* __restrict__ ad1, const float* __restrict__ ad2,
    const float* __restrict__ W3, const float* __restrict__ b3p,
    const int* __restrict__ ei, const int* __restrict__ ej,
    float* __restrict__ out) {
  __shared__ f16 wfr[17408];          // Wd1 ksteps 0..16: 34,816 B
  __shared__ u32 zbuf[4][1152];       // per-wave z staging: 18,432 B
  {
    float4* dst = (float4*)wfr;
    const float4* src = (const float4*)wq;
    for (int i = threadIdx.x; i < 2176; i += 256) dst[i] = src[i];
  }
  __syncthreads();
  const int lane = threadIdx.x & 63;
  const int wid  = threadIdx.x >> 6;
  const int c = lane & 31, h2 = lane >> 5;
  u32* zb = zbuf[wid];
  // register-resident frags: Wd1 kstep 17 + all Wd2
  f16x8 bp5[2];
  bp5[0] = *(const f16x8*)(wq + ((34+0)*64 + lane)*4);
  bp5[1] = *(const f16x8*)(wq + ((34+1)*64 + lane)*4);
  f16x8 w2f[4][2];
#pragma unroll
  for (int t2 = 0; t2 < 4; ++t2) {
    w2f[t2][0] = *(const f16x8*)(wq + 9216 + ((t2*2+0)*64 + lane)*4);
    w2f[t2][1] = *(const f16x8*)(wq + 9216 + ((t2*2+1)*64 + lane)*4);
  }
  const float b1x = b1[c], b1y = b1[c+32];
  const float b2x = b2[c], b2y = b2[c+32];
  const float a1 = *ad1, a2 = *ad2, b3 = *b3p;
  const f16x2 a1v = pkrtz(a1, a1);
  const f16x2 a2v = pkrtz(a2, a2);
  const f16x2 w3p = pkrtz(W3[c], W3[c+32]);
  const f16x2 ones2 = pkrtz(1.f, 1.f);

  for (int tile = blockIdx.x; tile < NTILES; tile += NBLK) {
    const int rbase = tile*256 + wid*64;
    const f16* pi[2]; const f16* pj[2];
    bool valid[2];
#pragma unroll
    for (int m = 0; m < 2; ++m) {
      int r = rbase + 32*m + c;
      valid[m] = (r < ROWS);
      unsigned rr = valid[m] ? (unsigned)r : (unsigned)(ROWS-1);
      unsigned bb = rr / (unsigned)EDGES;
      int e = (int)(rr - bb*(unsigned)EDGES);
      int ii = ei[e], jj = ej[e];
      pi[m] = hbuf + (((int)bb*NN + ii)*HID + 8*h2);
      pj[m] = hbuf + (((int)bb*NN + jj)*HID + 8*h2);
    }
    f32x16 acc[2][2];
#pragma unroll
    for (int r = 0; r < 16; ++r) {
      acc[0][0][r] = b1x; acc[0][1][r] = b1y;
      acc[1][0][r] = b1x; acc[1][1][r] = b1y;
    }
    // layer 1: K=288 = 6 octet-steps x {sum, absdiff, prod}
#pragma unroll
    for (int t = 0; t < 6; ++t) {
      f16x8 bs0 = *(const f16x8*)(wfr + (((t   )*2+0)*64 + lane)*8);
      f16x8 bs1 = *(const f16x8*)(wfr + (((t   )*2+1)*64 + lane)*8);
      f16x8 bd0 = *(const f16x8*)(wfr + (((t+ 6)*2+0)*64 + lane)*8);
      f16x8 bd1 = *(const f16x8*)(wfr + (((t+ 6)*2+1)*64 + lane)*8);
      f16x8 bp0 = (t < 5) ? *(const f16x8*)(wfr + (((t+12)*2+0)*64 + lane)*8) : bp5[0];
      f16x8 bp1 = (t < 5) ? *(const f16x8*)(wfr + (((t+12)*2+1)*64 + lane)*8) : bp5[1];
#pragma unroll
      for (int m = 0; m < 2; ++m) {
        f16x8 hi = *(const f16x8*)(pi[m] + 16*t);
        f16x8 hj = *(const f16x8*)(pj[m] + 16*t);
        f16x8 su = hi + hj;
        f16x8 di = habs8(hi - hj);
        f16x8 pr = hi * hj;
        acc[m][0] = __builtin_amdgcn_mfma_f32_32x32x16_f16(su, bs0, acc[m][0], 0,0,0);
        acc[m][1] = __builtin_amdgcn_mfma_f32_32x32x16_f16(su, bs1, acc[m][1], 0,0,0);
        acc[m][0] = __builtin_amdgcn_mfma_f32_32x32x16_f16(di, bd0, acc[m][0], 0,0,0);
        acc[m][1] = __builtin_amdgcn_mfma_f32_32x32x16_f16(di, bd1, acc[m][1], 0,0,0);
        acc[m][0] = __builtin_amdgcn_mfma_f32_32x32x16_f16(pr, bp0, acc[m][0], 0,0,0);
        acc[m][1] = __builtin_amdgcn_mfma_f32_32x32x16_f16(pr, bp1, acc[m][1], 0,0,0);
      }
    }
#pragma unroll
    for (int m = 0; m < 2; ++m) {
      // prelu(z1) packed-f16 -> LDS pairs (d, d+32) at dword [row][c], stride 36
#pragma unroll
      for (int r = 0; r < 16; ++r) {
        f16x2 p = pkrtz(acc[m][0][r], acc[m][1][r]);
        p = __builtin_elementwise_max(p, p * a1v);
        C2 cv; cv.h = p;
        int row = (r & 3) + 8*(r >> 2) + 4*h2;
        zb[row*36 + c] = cv.u;
      }
      // read back as layer-2 A-frags (edge = c): permuted-K contiguous, aligned b128
      f16x8 za[4];
#pragma unroll
      for (int t2 = 0; t2 < 4; ++t2)
        za[t2] = *(const f16x8*)((const f16*)zb + (c*36 + 8*t2 + 4*h2)*2);
      f32x16 zacc[2];
#pragma unroll
      for (int r = 0; r < 16; ++r) { zacc[0][r] = b2x; zacc[1][r] = b2y; }
#pragma unroll
      for (int t2 = 0; t2 < 4; ++t2) {
        zacc[0] = __builtin_amdgcn_mfma_f32_32x32x16_f16(za[t2], w2f[t2][0], zacc[0], 0,0,0);
        zacc[1] = __builtin_amdgcn_mfma_f32_32x32x16_f16(za[t2], w2f[t2][1], zacc[1], 0,0,0);
      }
      // prelu(z2)*W3 packed -> LDS -> per-edge dot2 sum
#pragma unroll
      for (int r = 0; r < 16; ++r) {
        f16x2 p = pkrtz(zacc[0][r], zacc[1][r]);
        p = __builtin_elementwise_max(p, p * a2v);
        p = p * w3p;
        C2 cv; cv.h = p;
        int row = (r & 3) + 8*(r >> 2) + 4*h2;
        zb[row*36 + c] = cv.u;
      }
      float ssum = 0.f;
#pragma unroll
      for (int g = 0; g < 4; ++g) {
        H8 v; v.h = *(const f16x8*)((const f16*)zb + (c*36 + 16*h2 + 4*g)*2);
#pragma unroll
        for (int dw = 0; dw < 4; ++dw)
          ssum = fdot2a(v.p[dw], ones2, ssum);
      }
      ssum += __shfl_xor(ssum, 32);
      if (h2 == 0 && valid[m]) out[rbase + 32*m + c] = ssum + b3;
    }
  }
}

extern "C" void kernel_launch(void* const* d_in, const int* in_sizes, int n_in,
                              void* d_out, int out_size, void* d_ws, size_t ws_size,
                              hipStream_t stream) {
  const float* nf  = (const float*)d_in[1];
  const float* sc  = (const float*)d_in[2];
  const float* sm  = (const float*)d_in[3];
  const float* ss  = (const float*)d_in[4];
  const float* We1 = (const float*)d_in[5];
  const float* be1 = (const float*)d_in[6];
  const float* ae1 = (const float*)d_in[7];
  const float* We2 = (const float*)d_in[8];
  const float* be2 = (const float*)d_in[9];
  const float* ae2 = (const float*)d_in[10];
  const float* W1  = (const float*)d_in[11];
  const float* b1  = (const float*)d_in[12];
  const float* a1  = (const float*)d_in[13];
  const float* W2  = (const float*)d_in[14];
  const float* b2  = (const float*)d_in[15];
  const float* a2  = (const float*)d_in[16];
  const float* W3  = (const float*)d_in[17];
  const float* b3  = (const float*)d_in[18];
  const int*   ei  = (const int*)d_in[19];
  const int*   ej  = (const int*)d_in[20];
  float* out = (float*)d_out;

  char* ws = (char*)d_ws;
  float* msum = (float*)ws;                              // 64 B
  f16*   g1   = (f16*)(ws + 64);                         // 1,228,800 B
  f16*   hbuf = (f16*)(ws + 64 + 1228800);               // 1,228,800 B
  u32*   wq   = (u32*)(ws + 64 + 2*1228800);             // 143,360 B

  prep_kernel<<<140, 256, 0, stream>>>(We1, We2, W1, W2, wq, msum);
  mean_kernel<<<64, 256, 0, stream>>>(sc, msum);
  enc1_kernel<<<50, 256, 0, stream>>>(sc, nf, sm, ss, be1, ae1, msum, wq, g1);
  enc2_kernel<<<50, 256, 0, stream>>>(g1, be2, ae2, wq, hbuf);
  decoder_kernel<<<NBLK, 256, 0, stream>>>(hbuf, wq, b1, b2, a1, a2, W3, b3,
                                           ei, ej, out);
}

// Round 4
// 193.676 us; speedup vs baseline: 1.3862x; 1.3862x over previous
//
#include <hip/hip_runtime.h>

#define NN 400
#define HID 96
#define EDGES 79800
#define BATCH 16
#define ROWS (BATCH*EDGES)
#define NTILES 4988
#define NBLK 512

typedef _Float16 f16;
typedef f16 f16x2 __attribute__((ext_vector_type(2)));
typedef f16 f16x8 __attribute__((ext_vector_type(8)));
typedef __fp16 fp16x2 __attribute__((ext_vector_type(2)));
typedef float f32x16 __attribute__((ext_vector_type(16)));
typedef unsigned int u32;

union H8 { f16x8 h; u32 u[4]; f16x2 p[4]; fp16x2 q[4]; };
union C2 { f16x2 h; fp16x2 q; u32 u; };

__device__ inline f16x2 pkrtz(float a, float b) {
  C2 c; c.q = __builtin_amdgcn_cvt_pkrtz(a, b); return c.h;
}
__device__ inline u32 pkrtz_u(float a, float b) {
  C2 c; c.q = __builtin_amdgcn_cvt_pkrtz(a, b); return c.u;
}
__device__ inline float fdot2a(f16x2 a, f16x2 b, float c) {
#if __has_builtin(__builtin_amdgcn_fdot2)
  C2 ca, cb; ca.h = a; cb.h = b;
  return __builtin_amdgcn_fdot2(ca.q, cb.q, c, false);
#else
  return c + (float)a.x*(float)b.x + (float)a.y*(float)b.y;
#endif
}

__device__ inline f16x8 habs8(f16x8 x) {
  H8 t; t.h = x;
  t.u[0] &= 0x7fff7fffu; t.u[1] &= 0x7fff7fffu;
  t.u[2] &= 0x7fff7fffu; t.u[3] &= 0x7fff7fffu;
  return t.h;
}

__device__ inline f16x8 pack8(float a0,float a1,float a2,float a3,
                              float a4,float a5,float a6,float a7){
  H8 u;
  u.p[0] = pkrtz(a0,a1);
  u.p[1] = pkrtz(a2,a3);
  u.p[2] = pkrtz(a4,a5);
  u.p[3] = pkrtz(a6,a7);
  return u.h;
}

// ---------------- fused prep (blocks 0..139) + per-batch partial mean (blocks 140..203) ---------
// wq regions (dwords): Wd1 [0,9216)  Wd2-permK [9216,11264)  We1 [11264,31232)  We2 [31232,35840)
// mpart[64]: 4 partial sums per batch (no atomics, no zero-init race).
__global__ void prep_mean_kernel(const float* __restrict__ We1, const float* __restrict__ We2,
                                 const float* __restrict__ W1, const float* __restrict__ W2,
                                 const float* __restrict__ sc,
                                 u32* __restrict__ wq, float* __restrict__ mpart) {
  if (blockIdx.x >= 140) {
    int p = blockIdx.x - 140;           // 0..63
    int b = p >> 2, part = p & 3;
    const float4* src = (const float4*)(sc + (size_t)b*160000) + part*10000;
    float s = 0.f;
    for (int i = threadIdx.x; i < 10000; i += 256) {
      float4 v = src[i];
      s += (v.x + v.y) + (v.z + v.w);
    }
    __shared__ float red[256];
    red[threadIdx.x] = s; __syncthreads();
    for (int off = 128; off > 0; off >>= 1) {
      if (threadIdx.x < off) red[threadIdx.x] += red[threadIdx.x + off];
      __syncthreads();
    }
    if (threadIdx.x == 0) mpart[p] = red[0];
    return;
  }
  int D = blockIdx.x*256 + threadIdx.x;     // 0..35839
  float v0, v1;
  if (D < 9216) {               // W_d1 B-frags (288 x 64), d = 32q+c
    int frag = D >> 8;  int t = frag >> 1, q = frag & 1;
    int rem = D & 255;  int lane = rem >> 2, dj = rem & 3;
    int c = lane & 31, h2 = lane >> 5;
    int k = 16*t + 8*h2 + 2*dj;
    int d = 32*q + c;
    v0 = W1[k*64 + d]; v1 = W1[(k+1)*64 + d];
  } else if (D < 11264) {       // W_d2 B-frags, K permuted: pair sources (p, p+32)
    int Dl = D - 9216;
    int frag = Dl >> 8; int t2 = frag >> 1, q = frag & 1;
    int rem = Dl & 255; int lane = rem >> 2, dj = rem & 3;
    int c = lane & 31, h2 = lane >> 5;
    int p = 8*t2 + 4*h2 + dj;
    int d = 32*q + c;
    v0 = W2[p*64 + d]; v1 = W2[(p+32)*64 + d];
  } else if (D < 31232) {       // W_e1 frags (416 x 96), feature-permuted (sc first, static at 400)
    int Dl = D - 11264;
    int frag = Dl >> 8; int t = frag/3, ct = frag - 3*t;
    int rem = Dl & 255; int lane = rem >> 2, dj = rem & 3;
    int c = lane & 31, h2 = lane >> 5;
    int k0 = 16*t + 8*h2 + 2*dj, k1 = k0 + 1;
    int d = 32*ct + c;
    v0 = (k0 < 400) ? We1[(8+k0)*96 + d] : (k0 < 408 ? We1[(k0-400)*96 + d] : 0.f);
    v1 = (k1 < 400) ? We1[(8+k1)*96 + d] : (k1 < 408 ? We1[(k1-400)*96 + d] : 0.f);
  } else {                      // W_e2 frags (96 x 96)
    int Dl = D - 31232;
    int frag = Dl >> 8; int t = frag/3, ct = frag - 3*t;
    int rem = Dl & 255; int lane = rem >> 2, dj = rem & 3;
    int c = lane & 31, h2 = lane >> 5;
    int k = 16*t + 8*h2 + 2*dj;
    int d = 32*ct + c;
    v0 = We2[k*96 + d]; v1 = We2[(k+1)*96 + d];
  }
  wq[D] = pkrtz_u(v0, v1);
}

// ---------------- enc1: feats (JIT from sc/nf) @ We1 -> prelu -> g1 f16 [6400 x 96] -------------
// one wave per block, 200 blocks (spread across CUs; was 50 blocks x 4 waves)
__global__ __launch_bounds__(64) void enc1_kernel(
    const float* __restrict__ sc, const float* __restrict__ nf,
    const float* __restrict__ smean, const float* __restrict__ sstd,
    const float* __restrict__ be1, const float* __restrict__ ae1,
    const float* __restrict__ mpart, const u32* __restrict__ wq,
    f16* __restrict__ g1) {
  int lane = threadIdx.x;
  int rt = blockIdx.x;                  // 0..199
  int c = lane & 31, h2 = lane >> 5;
  int r = rt*32 + c;                    // flat row (b*400+n)
  int b = r / 400;
  float ms = mpart[4*b] + mpart[4*b+1] + mpart[4*b+2] + mpart[4*b+3];
  float rm = 1.f / fmaxf(ms*(1.f/160000.f), 1e-8f);
  float a = *ae1;
  f32x16 acc[3];
#pragma unroll
  for (int q = 0; q < 3; ++q) {
    float bv = be1[32*q + c];
#pragma unroll
    for (int i = 0; i < 16; ++i) acc[q][i] = bv;
  }
  const u32* wb = wq + 11264;
  const float* scr = sc + (size_t)r*400;
#pragma unroll 4
  for (int t = 0; t < 25; ++t) {
    int k0 = 16*t + 8*h2;
    float4 s0 = *(const float4*)(scr + k0);
    float4 s1 = *(const float4*)(scr + k0 + 4);
    f16x8 af = pack8(s0.x*rm, s0.y*rm, s0.z*rm, s0.w*rm,
                     s1.x*rm, s1.y*rm, s1.z*rm, s1.w*rm);
#pragma unroll
    for (int ct = 0; ct < 3; ++ct) {
      f16x8 bf = *(const f16x8*)(wb + ((t*3+ct)*64 + lane)*4);
      acc[ct] = __builtin_amdgcn_mfma_f32_32x32x16_f16(af, bf, acc[ct], 0,0,0);
    }
  }
  {
    // t = 25: k 400..407 = static features (h2==0), 408..415 = zero pad
    f16x8 af = {};
    if (h2 == 0) {
      float q0[8];
#pragma unroll
      for (int j = 0; j < 8; ++j)
        q0[j] = (nf[r*8 + j] - smean[j]) / (sstd[j] + 1e-8f);
      af = pack8(q0[0],q0[1],q0[2],q0[3],q0[4],q0[5],q0[6],q0[7]);
    }
#pragma unroll
    for (int ct = 0; ct < 3; ++ct) {
      f16x8 bf = *(const f16x8*)(wb + ((25*3+ct)*64 + lane)*4);
      acc[ct] = __builtin_amdgcn_mfma_f32_32x32x16_f16(af, bf, acc[ct], 0,0,0);
    }
  }
#pragma unroll
  for (int ct = 0; ct < 3; ++ct)
#pragma unroll
    for (int rr = 0; rr < 16; ++rr) {
      int row = (rr & 3) + 8*(rr >> 2) + 4*h2;
      float v = acc[ct][rr]; v = fmaxf(v, a*v);
      g1[(rt*32 + row)*96 + 32*ct + c] = (f16)v;
    }
}

// ---------------- enc2: g1 @ We2 -> prelu -> h f16 [6400 x 96] ----------------
__global__ __launch_bounds__(64) void enc2_kernel(
    const f16* __restrict__ g1, const float* __restrict__ be2,
    const float* __restrict__ ae2, const u32* __restrict__ wq,
    f16* __restrict__ hout) {
  int lane = threadIdx.x;
  int rt = blockIdx.x;
  int c = lane & 31, h2 = lane >> 5;
  int r = rt*32 + c;
  float a = *ae2;
  f32x16 acc[3];
#pragma unroll
  for (int q = 0; q < 3; ++q) {
    float bv = be2[32*q + c];
#pragma unroll
    for (int i = 0; i < 16; ++i) acc[q][i] = bv;
  }
  const u32* wb = wq + 31232;
#pragma unroll
  for (int t = 0; t < 6; ++t) {
    f16x8 af = *(const f16x8*)(g1 + r*96 + 16*t + 8*h2);
#pragma unroll
    for (int ct = 0; ct < 3; ++ct) {
      f16x8 bf = *(const f16x8*)(wb + ((t*3+ct)*64 + lane)*4);
      acc[ct] = __builtin_amdgcn_mfma_f32_32x32x16_f16(af, bf, acc[ct], 0,0,0);
    }
  }
#pragma unroll
  for (int ct = 0; ct < 3; ++ct)
#pragma unroll
    for (int rr = 0; rr < 16; ++rr) {
      int row = (rr & 3) + 8*(rr >> 2) + 4*h2;
      float v = acc[ct][rr]; v = fmaxf(v, a*v);
      hout[(rt*32 + row)*96 + 32*ct + c] = (f16)v;
    }
}

// ---------------- decoder: per-edge 3-layer MLP via f16 MFMA ----------------
// d-mapping: col c of acc q holds dim 32q+c. z1/z2 pack pairs (d, d+32) per dword;
// W_d2 K-order is permuted to match (done in prep).
// launch_bounds(256,2): (256,3) forces spills -> 288 MB scratch traffic (round-3 post-mortem).
__global__ __launch_bounds__(256, 2) void decoder_kernel(
    const f16* __restrict__ hbuf, const u32* __restrict__ wq,
    const float* __restrict__ b1, const float* __restrict__ b2,
    const float* __restrict__ ad1, const float* __restrict__ ad2,
    const float* __restrict__ W3, const float* __restrict__ b3p,
    const int* __restrict__ ei, const int* __restrict__ ej,
    float* __restrict__ out) {
  __shared__ f16 wfr[17408];          // Wd1 ksteps 0..16: 34,816 B
  __shared__ u32 zbuf[4][1152];       // per-wave z staging: 18,432 B
  {
    float4* dst = (float4*)wfr;
    const float4* src = (const float4*)wq;
    for (int i = threadIdx.x; i < 2176; i += 256) dst[i] = src[i];
  }
  __syncthreads();
  const int lane = threadIdx.x & 63;
  const int wid  = threadIdx.x >> 6;
  const int c = lane & 31, h2 = lane >> 5;
  u32* zb = zbuf[wid];
  // register-resident frags: Wd1 kstep 17 + all Wd2
  f16x8 bp5[2];
  bp5[0] = *(const f16x8*)(wq + ((34+0)*64 + lane)*4);
  bp5[1] = *(const f16x8*)(wq + ((34+1)*64 + lane)*4);
  f16x8 w2f[4][2];
#pragma unroll
  for (int t2 = 0; t2 < 4; ++t2) {
    w2f[t2][0] = *(const f16x8*)(wq + 9216 + ((t2*2+0)*64 + lane)*4);
    w2f[t2][1] = *(const f16x8*)(wq + 9216 + ((t2*2+1)*64 + lane)*4);
  }
  const float b1x = b1[c], b1y = b1[c+32];
  const float b2x = b2[c], b2y = b2[c+32];
  const float a1 = *ad1, a2 = *ad2, b3 = *b3p;
  const f16x2 a1v = pkrtz(a1, a1);
  const f16x2 a2v = pkrtz(a2, a2);
  const f16x2 w3p = pkrtz(W3[c], W3[c+32]);
  const f16x2 ones2 = pkrtz(1.f, 1.f);

  for (int tile = blockIdx.x; tile < NTILES; tile += NBLK) {
    const int rbase = tile*256 + wid*64;
    const f16* pi[2]; const f16* pj[2];
    bool valid[2];
#pragma unroll
    for (int m = 0; m < 2; ++m) {
      int r = rbase + 32*m + c;
      valid[m] = (r < ROWS);
      unsigned rr = valid[m] ? (unsigned)r : (unsigned)(ROWS-1);
      unsigned bb = rr / (unsigned)EDGES;
      int e = (int)(rr - bb*(unsigned)EDGES);
      int ii = ei[e], jj = ej[e];
      pi[m] = hbuf + (((int)bb*NN + ii)*HID + 8*h2);
      pj[m] = hbuf + (((int)bb*NN + jj)*HID + 8*h2);
    }
    f32x16 acc[2][2];
#pragma unroll
    for (int r = 0; r < 16; ++r) {
      acc[0][0][r] = b1x; acc[0][1][r] = b1y;
      acc[1][0][r] = b1x; acc[1][1][r] = b1y;
    }
    // layer 1: K=288 = 6 octet-steps x {sum, absdiff, prod}
#pragma unroll
    for (int t = 0; t < 6; ++t) {
      f16x8 bs0 = *(const f16x8*)(wfr + (((t   )*2+0)*64 + lane)*8);
      f16x8 bs1 = *(const f16x8*)(wfr + (((t   )*2+1)*64 + lane)*8);
      f16x8 bd0 = *(const f16x8*)(wfr + (((t+ 6)*2+0)*64 + lane)*8);
      f16x8 bd1 = *(const f16x8*)(wfr + (((t+ 6)*2+1)*64 + lane)*8);
      f16x8 bp0 = (t < 5) ? *(const f16x8*)(wfr + (((t+12)*2+0)*64 + lane)*8) : bp5[0];
      f16x8 bp1 = (t < 5) ? *(const f16x8*)(wfr + (((t+12)*2+1)*64 + lane)*8) : bp5[1];
#pragma unroll
      for (int m = 0; m < 2; ++m) {
        f16x8 hi = *(const f16x8*)(pi[m] + 16*t);
        f16x8 hj = *(const f16x8*)(pj[m] + 16*t);
        f16x8 su = hi + hj;
        f16x8 di = habs8(hi - hj);
        f16x8 pr = hi * hj;
        acc[m][0] = __builtin_amdgcn_mfma_f32_32x32x16_f16(su, bs0, acc[m][0], 0,0,0);
        acc[m][1] = __builtin_amdgcn_mfma_f32_32x32x16_f16(su, bs1, acc[m][1], 0,0,0);
        acc[m][0] = __builtin_amdgcn_mfma_f32_32x32x16_f16(di, bd0, acc[m][0], 0,0,0);
        acc[m][1] = __builtin_amdgcn_mfma_f32_32x32x16_f16(di, bd1, acc[m][1], 0,0,0);
        acc[m][0] = __builtin_amdgcn_mfma_f32_32x32x16_f16(pr, bp0, acc[m][0], 0,0,0);
        acc[m][1] = __builtin_amdgcn_mfma_f32_32x32x16_f16(pr, bp1, acc[m][1], 0,0,0);
      }
    }
#pragma unroll
    for (int m = 0; m < 2; ++m) {
      // prelu(z1) packed-f16 -> LDS pairs (d, d+32) at dword [row][c], stride 36
#pragma unroll
      for (int r = 0; r < 16; ++r) {
        f16x2 p = pkrtz(acc[m][0][r], acc[m][1][r]);
        p = __builtin_elementwise_max(p, p * a1v);
        C2 cv; cv.h = p;
        int row = (r & 3) + 8*(r >> 2) + 4*h2;
        zb[row*36 + c] = cv.u;
      }
      // read back as layer-2 A-frags (edge = c): permuted-K contiguous, aligned b128
      f16x8 za[4];
#pragma unroll
      for (int t2 = 0; t2 < 4; ++t2)
        za[t2] = *(const f16x8*)((const f16*)zb + (c*36 + 8*t2 + 4*h2)*2);
      f32x16 zacc[2];
#pragma unroll
      for (int r = 0; r < 16; ++r) { zacc[0][r] = b2x; zacc[1][r] = b2y; }
#pragma unroll
      for (int t2 = 0; t2 < 4; ++t2) {
        zacc[0] = __builtin_amdgcn_mfma_f32_32x32x16_f16(za[t2], w2f[t2][0], zacc[0], 0,0,0);
        zacc[1] = __builtin_amdgcn_mfma_f32_32x32x16_f16(za[t2], w2f[t2][1], zacc[1], 0,0,0);
      }
      // prelu(z2)*W3 packed -> LDS -> per-edge dot2 sum
#pragma unroll
      for (int r = 0; r < 16; ++r) {
        f16x2 p = pkrtz(zacc[0][r], zacc[1][r]);
        p = __builtin_elementwise_max(p, p * a2v);
        p = p * w3p;
        C2 cv; cv.h = p;
        int row = (r & 3) + 8*(r >> 2) + 4*h2;
        zb[row*36 + c] = cv.u;
      }
      float ssum = 0.f;
#pragma unroll
      for (int g = 0; g < 4; ++g) {
        H8 v; v.h = *(const f16x8*)((const f16*)zb + (c*36 + 16*h2 + 4*g)*2);
#pragma unroll
        for (int dw = 0; dw < 4; ++dw)
          ssum = fdot2a(v.p[dw], ones2, ssum);
      }
      ssum += __shfl_xor(ssum, 32);
      if (h2 == 0 && valid[m]) out[rbase + 32*m + c] = ssum + b3;
    }
  }
}

extern "C" void kernel_launch(void* const* d_in, const int* in_sizes, int n_in,
                              void* d_out, int out_size, void* d_ws, size_t ws_size,
                              hipStream_t stream) {
  const float* nf  = (const float*)d_in[1];
  const float* sc  = (const float*)d_in[2];
  const float* sm  = (const float*)d_in[3];
  const float* ss  = (const float*)d_in[4];
  const float* We1 = (const float*)d_in[5];
  const float* be1 = (const float*)d_in[6];
  const float* ae1 = (const float*)d_in[7];
  const float* We2 = (const float*)d_in[8];
  const float* be2 = (const float*)d_in[9];
  const float* ae2 = (const float*)d_in[10];
  const float* W1  = (const float*)d_in[11];
  const float* b1  = (const float*)d_in[12];
  const float* a1  = (const float*)d_in[13];
  const float* W2  = (const float*)d_in[14];
  const float* b2  = (const float*)d_in[15];
  const float* a2  = (const float*)d_in[16];
  const float* W3  = (const float*)d_in[17];
  const float* b3  = (const float*)d_in[18];
  const int*   ei  = (const int*)d_in[19];
  const int*   ej  = (const int*)d_in[20];
  float* out = (float*)d_out;

  char* ws = (char*)d_ws;
  float* mpart = (float*)ws;                             // 64 f32 = 256 B
  f16*   g1   = (f16*)(ws + 256);                        // 1,228,800 B
  f16*   hbuf = (f16*)(ws + 256 + 1228800);              // 1,228,800 B
  u32*   wq   = (u32*)(ws + 256 + 2*1228800);            // 143,360 B

  prep_mean_kernel<<<204, 256, 0, stream>>>(We1, We2, W1, W2, sc, wq, mpart);
  enc1_kernel<<<200, 64, 0, stream>>>(sc, nf, sm, ss, be1, ae1, mpart, wq, g1);
  enc2_kernel<<<200, 64, 0, stream>>>(g1, be2, ae2, wq, hbuf);
  decoder_kernel<<<NBLK, 256, 0, stream>>>(hbuf, wq, b1, b2, a1, a2, W3, b3,
                                           ei, ej, out);
}